// Round 1
// baseline (495.124 us; speedup 1.0000x reference)
//
#include <hip/hip_runtime.h>

typedef __attribute__((ext_vector_type(8))) short s16x8;
typedef __attribute__((ext_vector_type(4))) float f32x4;

// ---------------- bf16 helpers (RNE) ----------------
__device__ __forceinline__ unsigned short f2bf(float x) {
  unsigned u = __float_as_uint(x);
  u = (u + 0x7fffu + ((u >> 16) & 1u)) >> 16;
  return (unsigned short)u;
}
__device__ __forceinline__ float bflo(unsigned v) { return __uint_as_float(v << 16); }
__device__ __forceinline__ float bfhi(unsigned v) { return __uint_as_float(v & 0xffff0000u); }

// ---------------- ws layout (ushort units) ----------------
// feat_t[32768][64] bf16, then W0f[3][16][64][8], W1f[8][16][64][8], W2f[8][16][64][8]
#define FEAT_OFF 0
#define W0F_OFF  2097152
#define W1F_OFF  (W0F_OFF + 24576)
#define W2F_OFF  (W1F_OFF + 65536)
#define WS_TOTAL (W2F_OFF + 65536)

__global__ void liif_prep(const float* __restrict__ inp,
                          const float* __restrict__ W0,
                          const float* __restrict__ W1,
                          const float* __restrict__ W2,
                          unsigned short* __restrict__ ws) {
  int tid = blockIdx.x * 256 + threadIdx.x;
  if (tid < 2097152) {
    // feat_t[pos*64 + c] = inp[c*32768 + pos]  (tid = pos*64+c)
    int pos = tid >> 6, c = tid & 63;
    ws[FEAT_OFF + tid] = f2bf(inp[c * 32768 + pos]);
  } else if (tid < W1F_OFF) {
    int e = tid - W0F_OFF;
    int j = e & 7, L = (e >> 3) & 63, nt = (e >> 9) & 15, c = e >> 13;
    int k = c * 32 + (L >> 4) * 8 + j, n = nt * 16 + (L & 15);
    ws[tid] = (k < 71) ? f2bf(W0[k * 256 + n]) : (unsigned short)0;
  } else if (tid < W2F_OFF) {
    int e = tid - W1F_OFF;
    int j = e & 7, L = (e >> 3) & 63, nt = (e >> 9) & 15, c = e >> 13;
    int k = c * 32 + (L >> 4) * 8 + j, n = nt * 16 + (L & 15);
    ws[tid] = f2bf(W1[k * 256 + n]);
  } else if (tid < WS_TOTAL) {
    int e = tid - W2F_OFF;
    int j = e & 7, L = (e >> 3) & 63, nt = (e >> 9) & 15, c = e >> 13;
    int k = c * 32 + (L >> 4) * 8 + j, n = nt * 16 + (L & 15);
    ws[tid] = f2bf(W2[k * 256 + n]);
  }
}

// One GEMM layer: rows 0..63 (A in LDS, bf16), cols 0..255 (B frags in global),
// out = relu(acc + bias) -> H (LDS, stride 264). Each wave: 64 rows x 64 cols.
template<int KC>
__device__ __forceinline__ void run_layer(const unsigned short* __restrict__ Wf,
                                          const float* __restrict__ bias,
                                          const unsigned short* A, int astride,
                                          unsigned short* H,
                                          int wave, int quad, int l16, int lane) {
  f32x4 acc[4][4];
#pragma unroll
  for (int i = 0; i < 4; ++i)
#pragma unroll
    for (int j = 0; j < 4; ++j) acc[i][j] = (f32x4){0.f, 0.f, 0.f, 0.f};

#pragma unroll
  for (int c = 0; c < KC; ++c) {
    s16x8 a[4];
#pragma unroll
    for (int rt = 0; rt < 4; ++rt)
      a[rt] = *(const s16x8*)(A + (rt * 16 + l16) * astride + c * 32 + quad * 8);
#pragma unroll
    for (int ntl = 0; ntl < 4; ++ntl) {
      int nt = wave * 4 + ntl;
      s16x8 b = *(const s16x8*)(Wf + (((c * 16 + nt) * 64 + lane) << 3));
#pragma unroll
      for (int rt = 0; rt < 4; ++rt)
        acc[rt][ntl] = __builtin_amdgcn_mfma_f32_16x16x32_bf16(a[rt], b, acc[rt][ntl], 0, 0, 0);
    }
  }
  __syncthreads();  // all waves done reading A (may alias H)
#pragma unroll
  for (int ntl = 0; ntl < 4; ++ntl) {
    int col = (wave * 4 + ntl) * 16 + l16;
    float bv = bias[col];
#pragma unroll
    for (int rt = 0; rt < 4; ++rt) {
#pragma unroll
      for (int i = 0; i < 4; ++i) {
        int r = rt * 16 + quad * 4 + i;
        float h = fmaxf(acc[rt][ntl][i] + bv, 0.0f);
        H[r * 264 + col] = f2bf(h);
      }
    }
  }
  __syncthreads();
}

__global__ __launch_bounds__(256, 3)
void liif_main(const float* __restrict__ coord,
               const float* __restrict__ cell,
               const float* __restrict__ b0,
               const float* __restrict__ b1,
               const float* __restrict__ b2,
               const float* __restrict__ W3,
               const float* __restrict__ b3,
               const unsigned short* __restrict__ ws,
               float* __restrict__ out) {
  // LDS: x[64][104] bf16 (k padded 96, stride 104 -> bank-free b128 reads)
  //      h[64][264] bf16 (stride 264 -> bank-free), reused for h1/h2/h3 in place
  __shared__ __align__(16) unsigned short sm_x[64 * 104];
  __shared__ __align__(16) unsigned short sm_h[64 * 264];
  __shared__ float sm_area[64];
  __shared__ float sm_pred[64];

  const unsigned short* feat = ws + FEAT_OFF;
  const int tid = threadIdx.x;
  const int lane = tid & 63;
  const int wave = tid >> 6;
  const int quad = lane >> 4;
  const int l16 = lane & 15;

  // ---------------- sampling: 4 threads per row, 16 channels each ----------------
  {
    const int row = tid >> 2, p = tid & 3;
    const int ql = row >> 3, s = row & 7;
    const int q = blockIdx.x * 8 + ql;
    const float c0r = coord[q * 3 + 0], c1r = coord[q * 3 + 1], c2r = coord[q * 3 + 2];
    const float R = 0.03125f;  // rx=ry=rz = 1/32
    const float sh0 = ((s & 4) ? R : -R) + 1e-6f;
    const float sh1 = ((s & 2) ? R : -R) + 1e-6f;
    const float sh2 = ((s & 1) ? R : -R) + 1e-6f;
    const float LO = -1.0f + 1e-6f, HI = 1.0f - 1e-6f;
    float c0 = fminf(fmaxf(c0r + sh0, LO), HI);
    float c1 = fminf(fmaxf(c1r + sh1, LO), HI);
    float c2 = fminf(fmaxf(c2r + sh2, LO), HI);
    // channel0 -> z/D axis, channel1 -> y/H, channel2 -> x/W
    float z = (c0 + 1.0f) * 16.0f - 0.5f;
    float y = (c1 + 1.0f) * 16.0f - 0.5f;
    float x = (c2 + 1.0f) * 16.0f - 0.5f;
    float zf = floorf(z), yf = floorf(y), xf = floorf(x);
    float wz = z - zf, wy = y - yf, wx = x - xf;
    int z0 = min(max((int)zf, 0), 31), z1 = min(max((int)zf + 1, 0), 31);
    int y0 = min(max((int)yf, 0), 31), y1 = min(max((int)yf + 1, 0), 31);
    int x0 = min(max((int)xf, 0), 31), x1 = min(max((int)xf + 1, 0), 31);
    float wz0 = 1.0f - wz, wy0 = 1.0f - wy, wx0 = 1.0f - wx;

    float w[8] = { wz0 * wy0 * wx0, wz0 * wy0 * wx, wz0 * wy * wx0, wz0 * wy * wx,
                   wz  * wy0 * wx0, wz  * wy0 * wx, wz  * wy * wx0, wz  * wy * wx };
    int idx[8] = { (z0 * 32 + y0) * 32 + x0, (z0 * 32 + y0) * 32 + x1,
                   (z0 * 32 + y1) * 32 + x0, (z0 * 32 + y1) * 32 + x1,
                   (z1 * 32 + y0) * 32 + x0, (z1 * 32 + y0) * 32 + x1,
                   (z1 * 32 + y1) * 32 + x0, (z1 * 32 + y1) * 32 + x1 };

    float acc[16];
#pragma unroll
    for (int i = 0; i < 16; ++i) acc[i] = 0.0f;
#pragma unroll
    for (int corner = 0; corner < 8; ++corner) {
      const uint4* cp = (const uint4*)(feat + idx[corner] * 64 + p * 16);
      uint4 v0 = cp[0], v1 = cp[1];
      float wc = w[corner];
      unsigned vv[8] = { v0.x, v0.y, v0.z, v0.w, v1.x, v1.y, v1.z, v1.w };
#pragma unroll
      for (int d = 0; d < 8; ++d) {
        acc[2 * d]     += wc * bflo(vv[d]);
        acc[2 * d + 1] += wc * bfhi(vv[d]);
      }
    }
    unsigned pw[8];
#pragma unroll
    for (int d = 0; d < 8; ++d)
      pw[d] = (unsigned)f2bf(acc[2 * d]) | ((unsigned)f2bf(acc[2 * d + 1]) << 16);
    uint4* dst = (uint4*)(&sm_x[row * 104 + p * 16]);
    dst[0] = make_uint4(pw[0], pw[1], pw[2], pw[3]);
    dst[1] = make_uint4(pw[4], pw[5], pw[6], pw[7]);

    if (p == 0) {
      const float step = 2.0f / 31.0f;
      // q_coord channel mixing as in reference: ch0 from x-interp, ch2 from z-interp
      float qc0 = wx0 * (-1.0f + step * x0) + wx * (-1.0f + step * x1);
      float qc1 = wy0 * (-1.0f + step * y0) + wy * (-1.0f + step * y1);
      float qc2 = wz0 * (-1.0f + step * z0) + wz * (-1.0f + step * z1);
      float rel0 = (c0r - qc0) * 32.0f;
      float rel1 = (c1r - qc1) * 32.0f;
      float rel2 = (c2r - qc2) * 32.0f;
      sm_area[row] = fabsf(rel0 * rel1 * rel2) + 1e-9f;
      float cl0 = cell[q * 3 + 0], cl1 = cell[q * 3 + 1], cl2 = cell[q * 3 + 2];
      float ssq = fminf(fmaxf(8.0f / (fabsf(cl0 * cl1 * cl2) + 1e-8f), 1.0f), 64.0f);
      unsigned tw0 = (unsigned)f2bf(rel0) | ((unsigned)f2bf(rel1) << 16);
      unsigned tw1 = (unsigned)f2bf(rel2) | ((unsigned)f2bf(cl0 * 32.0f) << 16);
      unsigned tw2 = (unsigned)f2bf(cl1 * 32.0f) | ((unsigned)f2bf(cl2 * 32.0f) << 16);
      unsigned tw3 = (unsigned)f2bf(ssq);  // element 71 zero-padded
      uint4* d2 = (uint4*)(&sm_x[row * 104 + 64]);
      d2[0] = make_uint4(tw0, tw1, tw2, tw3);
      d2[1] = make_uint4(0, 0, 0, 0);
      d2[2] = make_uint4(0, 0, 0, 0);
      d2[3] = make_uint4(0, 0, 0, 0);
    }
  }
  __syncthreads();

  // ---------------- MLP layers (bf16 MFMA, fp32 accum) ----------------
  run_layer<3>(ws + W0F_OFF, b0, sm_x, 104, sm_h, wave, quad, l16, lane);
  run_layer<8>(ws + W1F_OFF, b1, sm_h, 264, sm_h, wave, quad, l16, lane);
  run_layer<8>(ws + W2F_OFF, b2, sm_h, 264, sm_h, wave, quad, l16, lane);

  // ---------------- layer 3: 256 -> 1 (fp32 VALU) ----------------
  {
    const int row = tid >> 2, p = tid & 3;
    const unsigned short* hp = sm_h + row * 264 + p * 64;
    float sum = 0.0f;
#pragma unroll
    for (int kk = 0; kk < 8; ++kk) {
      const uint4 v = *(const uint4*)(hp + kk * 8);
      const float* w = W3 + p * 64 + kk * 8;
      unsigned vv[4] = { v.x, v.y, v.z, v.w };
#pragma unroll
      for (int d = 0; d < 4; ++d) {
        sum += w[2 * d]     * bflo(vv[d]);
        sum += w[2 * d + 1] * bfhi(vv[d]);
      }
    }
    sum += __shfl_xor(sum, 1);
    sum += __shfl_xor(sum, 2);
    if (p == 0) sm_pred[row] = sum + b3[0];
  }
  __syncthreads();

  // ---------------- area-weighted combine (areas reversed) ----------------
  if (tid < 8) {
    const int ql = tid;
    float tot = 0.0f, ret = 0.0f;
#pragma unroll
    for (int s = 0; s < 8; ++s) tot += sm_area[ql * 8 + s];
#pragma unroll
    for (int s = 0; s < 8; ++s) ret += sm_pred[ql * 8 + s] * sm_area[ql * 8 + (7 - s)];
    out[blockIdx.x * 8 + ql] = ret / tot;
  }
}

extern "C" void kernel_launch(void* const* d_in, const int* in_sizes, int n_in,
                              void* d_out, int out_size, void* d_ws, size_t ws_size,
                              hipStream_t stream) {
  const float* inp   = (const float*)d_in[0];
  const float* coord = (const float*)d_in[1];
  const float* cell  = (const float*)d_in[2];
  const float* W0    = (const float*)d_in[3];
  const float* b0    = (const float*)d_in[4];
  const float* W1    = (const float*)d_in[5];
  const float* b1    = (const float*)d_in[6];
  const float* W2    = (const float*)d_in[7];
  const float* b2    = (const float*)d_in[8];
  const float* W3    = (const float*)d_in[9];
  const float* b3    = (const float*)d_in[10];
  unsigned short* ws = (unsigned short*)d_ws;
  float* out = (float*)d_out;

  const int Q = in_sizes[1] / 3;  // 131072
  hipLaunchKernelGGL(liif_prep, dim3((WS_TOTAL + 255) / 256), dim3(256), 0, stream,
                     inp, W0, W1, W2, ws);
  hipLaunchKernelGGL(liif_main, dim3(Q / 8), dim3(256), 0, stream,
                     coord, cell, b0, b1, b2, W3, b3, ws, out);
}